// Round 5
// baseline (574.002 us; speedup 1.0000x reference)
//
#include <hip/hip_runtime.h>
#include <cstdint>

#define MUL0 16
#define MUL1 8
#define NRBF 8
#define HID 64
#define WNUM 576
#define CUTOFF 5.0f
#define EPSF 1e-8f

#define INV_SQRT3 0.57735026918962576f
#define A_PATH    0.20412414523193154f   /* 1/sqrt(24) */
#define Q16       0.25f                  /* 1/sqrt(16) */
#define Q8        0.35355339059327373f   /* 1/sqrt(8)  */
#define PI_OVER_CUT 0.62831853071795865f /* pi/5 */

typedef _Float16 f16;
typedef _Float16 f16x8 __attribute__((ext_vector_type(8)));
typedef float f32x4 __attribute__((ext_vector_type(4)));

__device__ __forceinline__ float sigm(float x) { return 1.0f / (1.0f + __expf(-x)); }
__device__ __forceinline__ void atomAddF(float* p, float v) { unsafeAtomicAdd(p, v); }

// ---------------- prep: permuted W2 tiles ----------------
// 36 tiles x 16 cols x 64 k (f16). Wave w owns tiles [9w, 9w+9):
//   s=0..3 : path1 (w1: 16i x 16j)  cols: i = 4s+(c>>2),     j = 4w+(c&3)
//   s=4..5 : path2 (w2:  8i x 16j)  cols: i = 4(s-4)+(c>>2), j = 4w+(c&3)
//   s=6..7 : path3 (w3: 16i x  8j)  cols: i = 8(s-6)+(c>>1), j = 2w+(c&1)
//   s=8    : path4 (w4:  8i x  8j)  cols: i = (c>>1),        j = 2w+(c&1)
// i-sums close in-wave via shfl_xor folds over the c bits carrying i.
extern "C" __global__ __launch_bounds__(256) void k_prep_w2t(
    const float* __restrict__ w_r2, const float* __restrict__ b_r2,
    f16* __restrict__ W2TP, float* __restrict__ biasP) {
  int tid = blockIdx.x * 256 + threadIdx.x;
  if (tid >= 36 * 16 * 64) return;
  int k = tid & 63, c = (tid >> 6) & 15, T = tid >> 10;
  int w = T / 9, s = T % 9;
  int n;
  if (s < 4)      n = (4 * s + (c >> 2)) * 16 + (4 * w + (c & 3));
  else if (s < 6) n = 256 + (4 * (s - 4) + (c >> 2)) * 16 + (4 * w + (c & 3));
  else if (s < 8) n = 384 + (8 * (s - 6) + (c >> 1)) * 8 + (2 * w + (c & 1));
  else            n = 512 + (c >> 1) * 8 + (2 * w + (c & 1));
  W2TP[tid] = (f16)w_r2[k * WNUM + n];
  if (k == 0) biasP[T * 16 + c] = b_r2[n];
}

// ---------------- node irrep norm (float4 vectorized) ----------------
extern "C" __global__ __launch_bounds__(256) void k_xnorm(
    const float* __restrict__ x, float* __restrict__ xnorm, int N) {
  int n = blockIdx.x * 256 + threadIdx.x;
  if (n >= N) return;
  const float4* xr = (const float4*)(x + (long long)n * 40);
  float4 u[10];
#pragma unroll
  for (int i = 0; i < 10; i++) u[i] = xr[i];
  const float* f = (const float*)u;
  float ss = 0.f, vs = 0.f;
#pragma unroll
  for (int i = 0; i < 16; i++) ss += f[i] * f[i];
#pragma unroll
  for (int i = 16; i < 40; i++) vs += f[i] * f[i];
  float sr = rsqrtf(ss * (1.0f / 16.0f) + EPSF);
  float vr = rsqrtf(vs * (1.0f / 8.0f) + EPSF);
  float o[40];
#pragma unroll
  for (int i = 0; i < 16; i++) o[i] = f[i] * sr;
#pragma unroll
  for (int i = 16; i < 40; i++) o[i] = f[i] * vr;
  float4* op = (float4*)(xnorm + (long long)n * 40);
#pragma unroll
  for (int i = 0; i < 10; i++) op[i] = ((const float4*)o)[i];
}

// ---------------- fused edge kernel ----------------
// block = 256 = 4 waves, 64 edges. Wave w owns output-j group w for ALL 64
// edges; its 9 B-tiles live in VGPRs for the whole kernel (loaded at entry,
// latency hidden behind phase A). Phase B: zero global loads.
extern "C" __global__ __launch_bounds__(256) void k_edge(
    const float* __restrict__ xnorm, const int* __restrict__ esrc,
    const int* __restrict__ edst, const float* __restrict__ sh,
    const float* __restrict__ rbf, const float* __restrict__ elen,
    const float* __restrict__ w_r1, const float* __restrict__ b_r1,
    const float* __restrict__ w_g1, const float* __restrict__ b_g1,
    const float* __restrict__ w_g2, const float* __restrict__ b_g2,
    const f16* __restrict__ W2TP, const float* __restrict__ biasP,
    float* __restrict__ agg0, float* __restrict__ agg1,
    float* __restrict__ normb, int E) {
  __shared__ float s_rbf[64][12];
  __shared__ float s_shT[4][64];
  __shared__ int s_dst[64];
  __shared__ float s_ew[64];
  __shared__ float s_gp[64][5];
  __shared__ float s_a0T[16][68];  // s * sh0        (stride 68: rows hit distinct banks)
  __shared__ float s_a1T[8][68];   // INV_SQRT3 * (v . sh1)
  __shared__ float s_snT[16][68];  // raw s
  __shared__ float s_vT[24][68];   // raw v
  __shared__ __align__(16) f16 s_H[64][64];
  __shared__ float s_bp[WNUM];

  const int t = threadIdx.x;
  const long long eb = (long long)blockIdx.x * 64;
  const int lane = t & 63;
  const int wv = t >> 6;
  const int quad = lane >> 4;
  const int c = lane & 15;

  // ---- B-tiles: 18 global loads issued NOW, consumed in phase B ----
  const f16* wbase = W2TP + (wv * 9) * 1024 + c * 64 + quad * 8;
  f16x8 B0[9], B1[9];
#pragma unroll
  for (int s = 0; s < 9; s++) {
    B0[s] = *(const f16x8*)(wbase + s * 1024);
    B1[s] = *(const f16x8*)(wbase + s * 1024 + 32);
  }

  // ---- gather issue: registers only, consumed at A2 ----
  const int e2 = t >> 2, q = t & 3;
  long long ge = eb + e2; if (ge >= E) ge = E - 1;
  const int src = esrc[ge];
  const float* xr = xnorm + (long long)src * 40;
  float4 g0, g1, g2, shv;
  if (q < 2) {
    g0 = ((const float4*)xr)[q * 2];
    g1 = ((const float4*)xr)[q * 2 + 1];
  } else {
    const float4* p = (const float4*)(xr + 16 + (q - 2) * 12);
    g0 = p[0]; g1 = p[1]; g2 = p[2];
    shv = ((const float4*)sh)[ge];
  }

  // ---- A1 weights into regs ----
  float wr[NRBF];
  const int h = t & 63;
#pragma unroll
  for (int r = 0; r < NRBF; r++) wr[r] = w_r1[r * HID + h];
  const float bh = b_r1[h];

  // ---- phase 0: stage LDS ----
  for (int i = t; i < 64 * NRBF; i += 256) {
    long long g = eb * NRBF + i;
    s_rbf[i >> 3][i & 7] = (g < (long long)E * NRBF) ? rbf[g] : 0.f;
  }
  {
    long long g = eb * 4 + t;
    s_shT[t & 3][t >> 2] = (g < (long long)E * 4) ? sh[g] : 0.f;
  }
  for (int i = t; i < WNUM; i += 256) s_bp[i] = biasP[i];
  if (t < 64) {
    long long g = eb + t;
    s_dst[t] = (g < E) ? edst[g] : 0;
  }
  __syncthreads();

  // ---- A1: H = silu(rbf @ w_r1 + b) ----
  {
    const int grp = t >> 6;
#pragma unroll
    for (int u = 0; u < 16; u++) {
      const int e = grp * 16 + u;
      float4 ra = *(const float4*)&s_rbf[e][0];
      float4 rb = *(const float4*)&s_rbf[e][4];
      float acc = bh + ra.x * wr[0] + ra.y * wr[1] + ra.z * wr[2] + ra.w * wr[3] +
                  rb.x * wr[4] + rb.y * wr[5] + rb.z * wr[6] + rb.w * wr[7];
      s_H[e][h] = (f16)(acc * sigm(acc));
    }
  }

  // ---- A2: commit gathered values ----
  if (q < 2) {
    const float sh0 = s_shT[0][e2];
    float vals[8] = {g0.x, g0.y, g0.z, g0.w, g1.x, g1.y, g1.z, g1.w};
    const int i0 = q * 8;
#pragma unroll
    for (int k = 0; k < 8; k++) {
      s_snT[i0 + k][e2] = vals[k];
      s_a0T[i0 + k][e2] = vals[k] * sh0;
    }
  } else {
    float vals[12] = {g0.x, g0.y, g0.z, g0.w, g1.x, g1.y,
                      g1.z, g1.w, g2.x, g2.y, g2.z, g2.w};
    const int i0 = (q - 2) * 4;
#pragma unroll
    for (int k = 0; k < 4; k++) {
      float vx = vals[3 * k], vy = vals[3 * k + 1], vz = vals[3 * k + 2];
      s_a1T[i0 + k][e2] = INV_SQRT3 * (vx * shv.y + vy * shv.z + vz * shv.w);
      s_vT[(i0 + k) * 3 + 0][e2] = vx;
      s_vT[(i0 + k) * 3 + 1][e2] = vy;
      s_vT[(i0 + k) * 3 + 2][e2] = vz;
    }
  }

  // ---- A3: gate MLP partials ----
  {
    const int e = t & 63, qq = t >> 6;
    float rb[NRBF];
#pragma unroll
    for (int r = 0; r < NRBF; r++) rb[r] = s_rbf[e][r];
    float acc = 0.f;
#pragma unroll
    for (int kk = 0; kk < 16; kk++) {
      int k = qq * 16 + kk;
      float tt = b_g1[k];
#pragma unroll
      for (int r = 0; r < NRBF; r++) tt += rb[r] * w_g1[r * HID + k];
      acc += tt * sigm(tt) * w_g2[k];
    }
    s_gp[e][qq] = acc;
  }
  __syncthreads();

  // ---- ew finalize ----
  if (t < 64) {
    long long g = eb + t;
    float acc = s_gp[t][0] + s_gp[t][1] + s_gp[t][2] + s_gp[t][3] + b_g2[0];
    float ew = 0.f;
    if (g < E) {
      float len = elen[g];
      float cw = (len < CUTOFF) ? 0.5f * (__cosf(PI_OVER_CUT * len) + 1.0f) : 0.f;
      ew = cw * sigm(acc);
    }
    s_ew[t] = ew;
  }
  __syncthreads();

  // ---- phase B: 4 subgroups x 9 register-resident tiles ----
#pragma unroll 1
  for (int g = 0; g < 4; g++) {
    const f16x8 af0 = *(const f16x8*)&s_H[g * 16 + c][quad * 8];
    const f16x8 af1 = *(const f16x8*)&s_H[g * 16 + c][32 + quad * 8];
    const int eoff = g * 16 + quad * 4;

    float m0r[4] = {0.f, 0.f, 0.f, 0.f};
    float t3r[4] = {0.f, 0.f, 0.f, 0.f};
    float m1xr[4] = {0.f, 0.f, 0.f, 0.f};
    float m1yr[4] = {0.f, 0.f, 0.f, 0.f};
    float m1zr[4] = {0.f, 0.f, 0.f, 0.f};

    // P1 (w1) + P2 (w2) -> m0
#pragma unroll
    for (int s = 0; s < 6; s++) {
      f32x4 C = {0.f, 0.f, 0.f, 0.f};
      C = __builtin_amdgcn_mfma_f32_16x16x32_f16(af0, B0[s], C, 0, 0, 0);
      C = __builtin_amdgcn_mfma_f32_16x16x32_f16(af1, B1[s], C, 0, 0, 0);
      const float bias = s_bp[(wv * 9 + s) * 16 + c];
      const float* arow = (s < 4) ? &s_a0T[4 * s + (c >> 2)][eoff]
                                  : &s_a1T[4 * (s - 4) + (c >> 2)][eoff];
      const f32x4 a = *(const f32x4*)arow;
#pragma unroll
      for (int r = 0; r < 4; r++) m0r[r] += a[r] * (C[r] + bias);
    }
    // P3 (w3) -> t3
#pragma unroll
    for (int s = 6; s < 8; s++) {
      f32x4 C = {0.f, 0.f, 0.f, 0.f};
      C = __builtin_amdgcn_mfma_f32_16x16x32_f16(af0, B0[s], C, 0, 0, 0);
      C = __builtin_amdgcn_mfma_f32_16x16x32_f16(af1, B1[s], C, 0, 0, 0);
      const float bias = s_bp[(wv * 9 + s) * 16 + c];
      const f32x4 a = *(const f32x4*)&s_snT[8 * (s - 6) + (c >> 1)][eoff];
#pragma unroll
      for (int r = 0; r < 4; r++) t3r[r] += a[r] * (C[r] + bias);
    }
    // P4 (w4) -> m1
    {
      f32x4 C = {0.f, 0.f, 0.f, 0.f};
      C = __builtin_amdgcn_mfma_f32_16x16x32_f16(af0, B0[8], C, 0, 0, 0);
      C = __builtin_amdgcn_mfma_f32_16x16x32_f16(af1, B1[8], C, 0, 0, 0);
      const float bias = s_bp[(wv * 9 + 8) * 16 + c];
      const int i = c >> 1;
      const f32x4 vx = *(const f32x4*)&s_vT[3 * i + 0][eoff];
      const f32x4 vy = *(const f32x4*)&s_vT[3 * i + 1][eoff];
      const f32x4 vz = *(const f32x4*)&s_vT[3 * i + 2][eoff];
#pragma unroll
      for (int r = 0; r < 4; r++) {
        const float wvv = C[r] + bias;
        m1xr[r] += vx[r] * wvv;
        m1yr[r] += vy[r] * wvv;
        m1zr[r] += vz[r] * wvv;
      }
    }

    // ---- folds: close the i-sums in-wave ----
#pragma unroll
    for (int r = 0; r < 4; r++) {
      m0r[r] += __shfl_xor(m0r[r], 4, 64);
      m0r[r] += __shfl_xor(m0r[r], 8, 64);
      t3r[r] += __shfl_xor(t3r[r], 2, 64);
      t3r[r] += __shfl_xor(t3r[r], 4, 64);
      t3r[r] += __shfl_xor(t3r[r], 8, 64);
      m1xr[r] += __shfl_xor(m1xr[r], 2, 64);
      m1xr[r] += __shfl_xor(m1xr[r], 4, 64);
      m1xr[r] += __shfl_xor(m1xr[r], 8, 64);
      m1yr[r] += __shfl_xor(m1yr[r], 2, 64);
      m1yr[r] += __shfl_xor(m1yr[r], 4, 64);
      m1yr[r] += __shfl_xor(m1yr[r], 8, 64);
      m1zr[r] += __shfl_xor(m1zr[r], 2, 64);
      m1zr[r] += __shfl_xor(m1zr[r], 4, 64);
      m1zr[r] += __shfl_xor(m1zr[r], 8, 64);
    }

    // ---- epilogue: wave w scatters its own j's ----
#pragma unroll
    for (int r = 0; r < 4; r++) {
      const int e = eoff + r;
      const float ew = s_ew[e];
      const float sc = A_PATH * ew;
      const float sh0 = s_shT[0][e];
      const int dst = s_dst[e];
      if (c < 4)
        atomAddF(&agg0[(long long)dst * 16 + 4 * wv + c], m0r[r] * sc);
      if (c < 2) {
        const float ox = sc * (t3r[r] * s_shT[1][e] + m1xr[r] * sh0);
        const float oy = sc * (t3r[r] * s_shT[2][e] + m1yr[r] * sh0);
        const float oz = sc * (t3r[r] * s_shT[3][e] + m1zr[r] * sh0);
        const long long b = (long long)dst * 24 + (2 * wv + c) * 3;
        atomAddF(&agg1[b], ox);
        atomAddF(&agg1[b + 1], oy);
        atomAddF(&agg1[b + 2], oz);
      }
      if (wv == 0 && c == 4) atomAddF(&normb[dst], ew);
    }
  }
}

// ---------------- final node kernel ----------------
extern "C" __global__ __launch_bounds__(256) void k_node(
    const float* __restrict__ x, const float* __restrict__ xnorm,
    const float* __restrict__ agg0, const float* __restrict__ agg1,
    const float* __restrict__ normb, const float* __restrict__ Wm_s,
    const float* __restrict__ Wm_v, const float* __restrict__ Wu_s,
    const float* __restrict__ Wu_v, const float* __restrict__ Ws_s,
    const float* __restrict__ Ws_v, const float* __restrict__ res_scale_p,
    float* __restrict__ out, int N) {
  __shared__ float sWms[16 * 24];
  __shared__ float sWmv[64];
  __shared__ float sWus[256];
  __shared__ float sWuv[64];
  __shared__ float sWss[256];
  __shared__ float sWsv[64];
  int t = threadIdx.x;
  for (int i = t; i < 384; i += 256) sWms[i] = Wm_s[i];
  for (int i = t; i < 64; i += 256) sWmv[i] = Wm_v[i];
  for (int i = t; i < 256; i += 256) sWus[i] = Wu_s[i];
  for (int i = t; i < 64; i += 256) sWuv[i] = Wu_v[i];
  for (int i = t; i < 256; i += 256) sWss[i] = Ws_s[i];
  for (int i = t; i < 64; i += 256) sWsv[i] = Ws_v[i];
  __syncthreads();
  int n = blockIdx.x * 256 + t;
  if (n >= N) return;

  float inv = 1.0f / fmaxf(normb[n], EPSF);
  float a0[16], a1[24];
  {
    const float4* p0 = (const float4*)(agg0 + (long long)n * 16);
#pragma unroll
    for (int i = 0; i < 4; i++) ((float4*)a0)[i] = p0[i];
    const float4* p1 = (const float4*)(agg1 + (long long)n * 24);
#pragma unroll
    for (int i = 0; i < 6; i++) ((float4*)a1)[i] = p1[i];
  }
#pragma unroll
  for (int i = 0; i < 16; i++) a0[i] *= inv;
#pragma unroll
  for (int i = 0; i < 24; i++) a1[i] *= inv;

  float scal[16], gate[8];
#pragma unroll
  for (int jj = 0; jj < 24; jj++) {
    float acc = 0.f;
#pragma unroll
    for (int i = 0; i < 16; i++) acc += a0[i] * sWms[i * 24 + jj];
    acc *= Q16;
    if (jj < 16) scal[jj] = acc * sigm(acc);
    else gate[jj - 16] = sigm(acc);
  }
  float vg[24];
#pragma unroll
  for (int j = 0; j < 8; j++) {
    float g = gate[j];
#pragma unroll
    for (int cc = 0; cc < 3; cc++) {
      float acc = 0.f;
#pragma unroll
      for (int i = 0; i < 8; i++) acc += a1[i * 3 + cc] * sWmv[i * 8 + j];
      vg[j * 3 + cc] = acc * Q8 * g;
    }
  }
  float xn[40], xo[40];
  {
    const float4* pn = (const float4*)(xnorm + (long long)n * 40);
    const float4* po = (const float4*)(x + (long long)n * 40);
#pragma unroll
    for (int i = 0; i < 10; i++) { ((float4*)xn)[i] = pn[i]; ((float4*)xo)[i] = po[i]; }
  }
  float rs = res_scale_p[0];
  float o[40];
#pragma unroll
  for (int j = 0; j < 16; j++) {
    float acc = 0.f, acc2 = 0.f;
#pragma unroll
    for (int i = 0; i < 16; i++) {
      acc += scal[i] * sWus[i * 16 + j];
      acc2 += xn[i] * sWss[i * 16 + j];
    }
    o[j] = xo[j] + rs * ((acc + acc2) * Q16);
  }
#pragma unroll
  for (int j = 0; j < 8; j++) {
#pragma unroll
    for (int cc = 0; cc < 3; cc++) {
      float acc = 0.f;
#pragma unroll
      for (int i = 0; i < 8; i++)
        acc += vg[i * 3 + cc] * sWuv[i * 8 + j] + xn[16 + i * 3 + cc] * sWsv[i * 8 + j];
      o[16 + j * 3 + cc] = xo[16 + j * 3 + cc] + rs * (acc * Q8);
    }
  }
  float4* op = (float4*)(out + (long long)n * 40);
#pragma unroll
  for (int i = 0; i < 10; i++) op[i] = ((const float4*)o)[i];
}

// ---------------- launch ----------------
extern "C" void kernel_launch(void* const* d_in, const int* in_sizes, int n_in,
                              void* d_out, int out_size, void* d_ws, size_t ws_size,
                              hipStream_t stream) {
  const float* x = (const float*)d_in[0];
  const int* esrc = (const int*)d_in[1];
  const int* edst = (const int*)d_in[2];
  const float* sh = (const float*)d_in[3];
  const float* rbf = (const float*)d_in[4];
  const float* elen = (const float*)d_in[5];
  const float* w_r1 = (const float*)d_in[6];
  const float* b_r1 = (const float*)d_in[7];
  const float* w_r2 = (const float*)d_in[8];
  const float* b_r2 = (const float*)d_in[9];
  const float* w_g1 = (const float*)d_in[10];
  const float* b_g1 = (const float*)d_in[11];
  const float* w_g2 = (const float*)d_in[12];
  const float* b_g2 = (const float*)d_in[13];
  const float* Wm_s = (const float*)d_in[14];
  const float* Wm_v = (const float*)d_in[15];
  const float* Wu_s = (const float*)d_in[16];
  const float* Wu_v = (const float*)d_in[17];
  const float* Ws_s = (const float*)d_in[18];
  const float* Ws_v = (const float*)d_in[19];
  const float* res_scale = (const float*)d_in[20];

  const int N = in_sizes[0] / 40;
  const int E = in_sizes[1];

  char* ws = (char*)d_ws;
  size_t off = 0;
  float* xnorm = (float*)(ws + off); off += (size_t)N * 40 * sizeof(float);
  off = (off + 255) & ~(size_t)255;
  float* agg0 = (float*)(ws + off); off += (size_t)N * 16 * sizeof(float);
  float* agg1 = (float*)(ws + off); off += (size_t)N * 24 * sizeof(float);
  float* normb = (float*)(ws + off); off += (size_t)N * sizeof(float);
  off = (off + 255) & ~(size_t)255;
  f16* W2TP = (f16*)(ws + off); off += (size_t)36 * 1024 * sizeof(f16);
  off = (off + 255) & ~(size_t)255;
  float* biasP = (float*)(ws + off); off += (size_t)WNUM * sizeof(float);

  // zero accumulators (agg0, agg1, normb are contiguous)
  hipMemsetAsync(agg0, 0, (size_t)N * 41 * sizeof(float), stream);

  k_prep_w2t<<<(36 * 16 * 64 + 255) / 256, 256, 0, stream>>>(w_r2, b_r2, W2TP, biasP);
  k_xnorm<<<(N + 255) / 256, 256, 0, stream>>>(x, xnorm, N);

  int nblk = (E + 63) / 64;
  k_edge<<<nblk, 256, 0, stream>>>(xnorm, esrc, edst, sh, rbf, elen, w_r1, b_r1,
                                   w_g1, b_g1, w_g2, b_g2, W2TP, biasP, agg0, agg1,
                                   normb, E);

  k_node<<<(N + 255) / 256, 256, 0, stream>>>(x, xnorm, agg0, agg1, normb, Wm_s,
                                              Wm_v, Wu_s, Wu_v, Ws_s, Ws_v,
                                              res_scale, (float*)d_out, N);
}

// Round 6
// 469.211 us; speedup vs baseline: 1.2233x; 1.2233x over previous
//
#include <hip/hip_runtime.h>
#include <cstdint>

#define MUL0 16
#define MUL1 8
#define NRBF 8
#define HID 64
#define WNUM 576
#define CUTOFF 5.0f
#define EPSF 1e-8f

#define INV_SQRT3 0.57735026918962576f
#define A_PATH    0.20412414523193154f   /* 1/sqrt(24) */
#define Q16       0.25f                  /* 1/sqrt(16) */
#define Q8        0.35355339059327373f   /* 1/sqrt(8)  */
#define PI_OVER_CUT 0.62831853071795865f /* pi/5 */

typedef _Float16 f16;
typedef _Float16 f16x8 __attribute__((ext_vector_type(8)));
typedef float f32x4 __attribute__((ext_vector_type(4)));

__device__ __forceinline__ float sigm(float x) { return 1.0f / (1.0f + __expf(-x)); }
__device__ __forceinline__ void atomAddF(float* p, float v) { unsafeAtomicAdd(p, v); }

// ---------------- prep: w_r2 (64 x 576 f32) -> W2T (576 x 64 f16) ----------------
extern "C" __global__ __launch_bounds__(256) void k_prep_w2t(
    const float* __restrict__ w_r2, f16* __restrict__ W2T) {
  int t = blockIdx.x * 256 + threadIdx.x;
  if (t >= HID * WNUM) return;
  int n = t >> 6, k = t & 63;
  W2T[n * 64 + k] = (f16)w_r2[k * WNUM + n];
}

// ---------------- node irrep norm ----------------
extern "C" __global__ __launch_bounds__(256) void k_xnorm(
    const float* __restrict__ x, float* __restrict__ xnorm, int N) {
  int n = blockIdx.x * 256 + threadIdx.x;
  if (n >= N) return;
  const float4* xr = (const float4*)(x + (long long)n * 40);
  float4 u[10];
#pragma unroll
  for (int i = 0; i < 10; i++) u[i] = xr[i];
  const float* f = (const float*)u;
  float ss = 0.f, vs = 0.f;
#pragma unroll
  for (int i = 0; i < 16; i++) ss += f[i] * f[i];
#pragma unroll
  for (int i = 16; i < 40; i++) vs += f[i] * f[i];
  float sr = rsqrtf(ss * (1.0f / 16.0f) + EPSF);
  float vr = rsqrtf(vs * (1.0f / 8.0f) + EPSF);
  float o[40];
#pragma unroll
  for (int i = 0; i < 16; i++) o[i] = f[i] * sr;
#pragma unroll
  for (int i = 16; i < 40; i++) o[i] = f[i] * vr;
  float4* op = (float4*)(xnorm + (long long)n * 40);
#pragma unroll
  for (int i = 0; i < 10; i++) op[i] = ((const float4*)o)[i];
}

// ---------------- counting sort by dst ----------------
extern "C" __global__ __launch_bounds__(256) void k_hist(
    const int* __restrict__ edst, int* __restrict__ cnt, int E) {
  int e = blockIdx.x * 256 + threadIdx.x;
  if (e < E) atomicAdd(&cnt[edst[e]], 1);
}

// per-block exclusive scan of cnt -> off, block totals -> bsum
extern "C" __global__ __launch_bounds__(256) void k_scan1(
    const int* __restrict__ cnt, int* __restrict__ off,
    int* __restrict__ bsum, int N) {
  __shared__ int s[256];
  int t = threadIdx.x, i = blockIdx.x * 256 + t;
  int v = (i < N) ? cnt[i] : 0;
  s[t] = v;
  __syncthreads();
  for (int o = 1; o < 256; o <<= 1) {
    int x = (t >= o) ? s[t - o] : 0;
    __syncthreads();
    s[t] += x;
    __syncthreads();
  }
  if (i < N) off[i] = s[t] - v;
  if (t == 255) bsum[blockIdx.x] = s[255];
}

// single block: exclusive scan of bsum -> bsumx (NB <= 256)
extern "C" __global__ __launch_bounds__(256) void k_scan2(
    const int* __restrict__ bsum, int* __restrict__ bsumx, int NB) {
  __shared__ int s[256];
  int t = threadIdx.x;
  int v = (t < NB) ? bsum[t] : 0;
  s[t] = v;
  __syncthreads();
  for (int o = 1; o < 256; o <<= 1) {
    int x = (t >= o) ? s[t - o] : 0;
    __syncthreads();
    s[t] += x;
    __syncthreads();
  }
  if (t < NB) bsumx[t] = s[t] - v;
}

extern "C" __global__ __launch_bounds__(256) void k_scan3(
    const int* __restrict__ off, const int* __restrict__ bsumx,
    int* __restrict__ cursor, int N) {
  int i = blockIdx.x * 256 + threadIdx.x;
  if (i < N) cursor[i] = off[i] + bsumx[blockIdx.x];
}

// permute + pre-gather all per-edge inputs into sorted-by-dst order
extern "C" __global__ __launch_bounds__(256) void k_perm(
    const int* __restrict__ esrc, const int* __restrict__ edst,
    const float* __restrict__ sh, const float* __restrict__ rbf,
    const float* __restrict__ elen, int* __restrict__ cursor,
    int* __restrict__ src_s, int* __restrict__ dst_s,
    float* __restrict__ sh_s, float* __restrict__ rbf_s,
    float* __restrict__ elen_s, int E) {
  int e = blockIdx.x * 256 + threadIdx.x;
  if (e >= E) return;
  int d = edst[e];
  int p = atomicAdd(&cursor[d], 1);
  src_s[p] = esrc[e];
  dst_s[p] = d;
  elen_s[p] = elen[e];
  ((float4*)sh_s)[p] = ((const float4*)sh)[e];
  ((float4*)rbf_s)[2 * p] = ((const float4*)rbf)[2 * e];
  ((float4*)rbf_s)[2 * p + 1] = ((const float4*)rbf)[2 * e + 1];
}

// ---------------- fused edge kernel (edges sorted by dst) ----------------
// block = 256 threads = 4 waves, 64 edges. Each wave owns 16 edges.
extern "C" __global__ __launch_bounds__(256) void k_edge(
    const float* __restrict__ xnorm, const int* __restrict__ src_s,
    const int* __restrict__ dst_s, const float* __restrict__ sh_s,
    const float* __restrict__ rbf_s, const float* __restrict__ elen_s,
    const float* __restrict__ w_r1, const float* __restrict__ b_r1,
    const float* __restrict__ w_g1, const float* __restrict__ b_g1,
    const float* __restrict__ w_g2, const float* __restrict__ b_g2,
    const float* __restrict__ b_r2, const f16* __restrict__ W2T,
    float* __restrict__ agg0, float* __restrict__ agg1,
    float* __restrict__ normb, int E) {
  __shared__ float s_rbf[64][12];        // stride 12: 16B-aligned rows for b128
  __shared__ float s_shT[4][64];
  __shared__ int s_dst[64];
  __shared__ float s_ew[64];
  __shared__ float s_gp[64][5];
  __shared__ float s_snT[16][64];        // raw s (sh0 factored into epilogue)
  __shared__ float s_a1T[8][64];
  __shared__ float s_vT[24][64];         // raw v (sh0 factored into epilogue)
  __shared__ __align__(16) f16 s_H[64][64];
  __shared__ float s_br2[WNUM];

  const int t = threadIdx.x;
  const long long eb = (long long)blockIdx.x * 64;

  // ---- gather issue: registers only, consumed at A2 ----
  const int e2 = t >> 2, q = t & 3;
  long long ge = eb + e2; if (ge >= E) ge = E - 1;
  const int src = src_s[ge];
  const float* xr = xnorm + (long long)src * 40;
  float4 g0, g1, g2, shv;
  if (q < 2) {
    g0 = ((const float4*)xr)[q * 2];
    g1 = ((const float4*)xr)[q * 2 + 1];
  } else {
    const float4* p = (const float4*)(xr + 16 + (q - 2) * 12);
    g0 = p[0]; g1 = p[1]; g2 = p[2];
    shv = ((const float4*)sh_s)[ge];
  }

  // ---- A1 weights into regs ----
  float wr[NRBF];
  const int h = t & 63;
#pragma unroll
  for (int r = 0; r < NRBF; r++) wr[r] = w_r1[r * HID + h];
  const float bh = b_r1[h];

  // ---- phase 0: stage LDS (all reads coalesced from sorted arrays) ----
  for (int i = t; i < 64 * NRBF; i += 256) {
    long long g = eb * NRBF + i;
    s_rbf[i >> 3][i & 7] = (g < (long long)E * NRBF) ? rbf_s[g] : 0.f;
  }
  {
    long long g = eb * 4 + t;
    s_shT[t & 3][t >> 2] = (g < (long long)E * 4) ? sh_s[g] : 0.f;
  }
  for (int i = t; i < WNUM; i += 256) s_br2[i] = b_r2[i];
  if (t < 64) {
    long long g = eb + t;
    s_dst[t] = (g < E) ? dst_s[g] : 0;
  }
  __syncthreads();

  // ---- A1: H = silu(rbf @ w_r1 + b) ----
  {
    const int grp = t >> 6;
#pragma unroll
    for (int u = 0; u < 16; u++) {
      const int e = grp * 16 + u;
      float4 ra = *(const float4*)&s_rbf[e][0];
      float4 rb = *(const float4*)&s_rbf[e][4];
      float acc = bh + ra.x * wr[0] + ra.y * wr[1] + ra.z * wr[2] + ra.w * wr[3] +
                  rb.x * wr[4] + rb.y * wr[5] + rb.z * wr[6] + rb.w * wr[7];
      s_H[e][h] = (f16)(acc * sigm(acc));
    }
  }

  // ---- A2: commit gathered values ----
  if (q < 2) {
    float vals[8] = {g0.x, g0.y, g0.z, g0.w, g1.x, g1.y, g1.z, g1.w};
    const int i0 = q * 8;
#pragma unroll
    for (int k = 0; k < 8; k++) s_snT[i0 + k][e2] = vals[k];
  } else {
    float vals[12] = {g0.x, g0.y, g0.z, g0.w, g1.x, g1.y,
                      g1.z, g1.w, g2.x, g2.y, g2.z, g2.w};
    const int i0 = (q - 2) * 4;
#pragma unroll
    for (int k = 0; k < 4; k++) {
      float vx = vals[3 * k], vy = vals[3 * k + 1], vz = vals[3 * k + 2];
      s_a1T[i0 + k][e2] = INV_SQRT3 * (vx * shv.y + vy * shv.z + vz * shv.w);
      s_vT[(i0 + k) * 3 + 0][e2] = vx;
      s_vT[(i0 + k) * 3 + 1][e2] = vy;
      s_vT[(i0 + k) * 3 + 2][e2] = vz;
    }
  }

  // ---- A3: gate MLP partials ----
  {
    const int e = t & 63, qq = t >> 6;
    float rb[NRBF];
#pragma unroll
    for (int r = 0; r < NRBF; r++) rb[r] = s_rbf[e][r];
    float acc = 0.f;
#pragma unroll
    for (int kk = 0; kk < 16; kk++) {
      int k = qq * 16 + kk;
      float tt = b_g1[k];
#pragma unroll
      for (int r = 0; r < NRBF; r++) tt += rb[r] * w_g1[r * HID + k];
      acc += tt * sigm(tt) * w_g2[k];
    }
    s_gp[e][qq] = acc;
  }

  // ---- prefetch first two B tiles ----
  const int lane = t & 63;
  const int wv = t >> 6;
  const int quad = lane >> 4;
  const int c = lane & 15;
  const int e0 = wv * 16;
  const f16* wb = W2T + c * 64 + quad * 8;
  f16x8 rb0[2], rb1[2];
  rb0[0] = *(const f16x8*)(wb);
  rb1[0] = *(const f16x8*)(wb + 32);
  rb0[1] = *(const f16x8*)(wb + 1024);
  rb1[1] = *(const f16x8*)(wb + 1024 + 32);

  __syncthreads();

  // ---- ew finalize ----
  if (t < 64) {
    long long g = eb + t;
    float acc = s_gp[t][0] + s_gp[t][1] + s_gp[t][2] + s_gp[t][3] + b_g2[0];
    float ew = 0.f;
    if (g < E) {
      float len = elen_s[g];
      float cw = (len < CUTOFF) ? 0.5f * (__cosf(PI_OVER_CUT * len) + 1.0f) : 0.f;
      ew = cw * sigm(acc);
    }
    s_ew[t] = ew;
  }

  const f16x8 af0 = *(const f16x8*)&s_H[e0 + c][quad * 8];
  const f16x8 af1 = *(const f16x8*)&s_H[e0 + c][32 + quad * 8];

  __syncthreads();

  // ---- phase B: depth-2 double-buffered MFMA over 36 j-tiles ----
  float m0s[4] = {0.f, 0.f, 0.f, 0.f};
  float m0v[4] = {0.f, 0.f, 0.f, 0.f};
  float t3a[4] = {0.f, 0.f, 0.f, 0.f};
  float m1x[4] = {0.f, 0.f, 0.f, 0.f};
  float m1y[4] = {0.f, 0.f, 0.f, 0.f};
  float m1z[4] = {0.f, 0.f, 0.f, 0.f};

#pragma unroll 2
  for (int jt = 0; jt < 36; jt++) {
    const int s = jt & 1;
    f16x8 b0 = rb0[s], b1 = rb1[s];
    if (jt + 2 < 36) {
      rb0[s] = *(const f16x8*)(wb + (jt + 2) * 1024);
      rb1[s] = *(const f16x8*)(wb + (jt + 2) * 1024 + 32);
    }
    f32x4 C = {0.f, 0.f, 0.f, 0.f};
    C = __builtin_amdgcn_mfma_f32_16x16x32_f16(af0, b0, C, 0, 0, 0);
    C = __builtin_amdgcn_mfma_f32_16x16x32_f16(af1, b1, C, 0, 0, 0);
    const float bias = s_br2[jt * 16 + c];
    if (jt < 16) {
      const f32x4 sv = *(const f32x4*)&s_snT[jt][e0 + quad * 4];
#pragma unroll
      for (int r = 0; r < 4; r++) m0s[r] += sv[r] * (C[r] + bias);
    } else if (jt < 24) {
      const f32x4 av = *(const f32x4*)&s_a1T[jt - 16][e0 + quad * 4];
#pragma unroll
      for (int r = 0; r < 4; r++) m0v[r] += av[r] * (C[r] + bias);
    } else if (jt < 32) {
      const int i = (jt - 24) * 2 + (c >> 3);
      const f32x4 sv = *(const f32x4*)&s_snT[i][e0 + quad * 4];
#pragma unroll
      for (int r = 0; r < 4; r++) t3a[r] += sv[r] * (C[r] + bias);
    } else {
      const int i = (jt - 32) * 2 + (c >> 3);
      const f32x4 vx4 = *(const f32x4*)&s_vT[3 * i + 0][e0 + quad * 4];
      const f32x4 vy4 = *(const f32x4*)&s_vT[3 * i + 1][e0 + quad * 4];
      const f32x4 vz4 = *(const f32x4*)&s_vT[3 * i + 2][e0 + quad * 4];
#pragma unroll
      for (int r = 0; r < 4; r++) {
        const float wvv = C[r] + bias;
        m1x[r] += vx4[r] * wvv;
        m1y[r] += vy4[r] * wvv;
        m1z[r] += vz4[r] * wvv;
      }
    }
  }

  // fold the two column-halves (c and c^8 share output j = c&7)
#pragma unroll
  for (int r = 0; r < 4; r++) {
    t3a[r] += __shfl_xor(t3a[r], 8, 64);
    m1x[r] += __shfl_xor(m1x[r], 8, 64);
    m1y[r] += __shfl_xor(m1y[r], 8, 64);
    m1z[r] += __shfl_xor(m1z[r], 8, 64);
  }

  // ---- epilogue: segmented flush over the 4-edge register window.
  //      Edges are sorted by dst, so equal-dst runs collapse to ONE atomic
  //      per (dst, col) per wave-quad: ~7x fewer fp32 atomics. ----
  {
    const int ebase = e0 + quad * 4;
    int dprev = s_dst[ebase];
    float a0a = 0.f, axa = 0.f, aya = 0.f, aza = 0.f, ewa = 0.f;
#pragma unroll
    for (int r = 0; r < 4; r++) {
      const int e = ebase + r;
      const int d = s_dst[e];
      if (d != dprev) {
        atomAddF(&agg0[(long long)dprev * 16 + c], a0a);
        if (c < 8) {
          const long long b = (long long)dprev * 24 + c * 3;
          atomAddF(&agg1[b], axa);
          atomAddF(&agg1[b + 1], aya);
          atomAddF(&agg1[b + 2], aza);
        } else if (c == 8) {
          atomAddF(&normb[dprev], ewa);
        }
        a0a = axa = aya = aza = ewa = 0.f;
        dprev = d;
      }
      const float ew = s_ew[e];
      const float sc = A_PATH * ew;
      const float sh0 = s_shT[0][e];
      a0a += (sh0 * m0s[r] + m0v[r]) * sc;
      axa += sc * (t3a[r] * s_shT[1][e] + m1x[r] * sh0);
      aya += sc * (t3a[r] * s_shT[2][e] + m1y[r] * sh0);
      aza += sc * (t3a[r] * s_shT[3][e] + m1z[r] * sh0);
      ewa += ew;
    }
    atomAddF(&agg0[(long long)dprev * 16 + c], a0a);
    if (c < 8) {
      const long long b = (long long)dprev * 24 + c * 3;
      atomAddF(&agg1[b], axa);
      atomAddF(&agg1[b + 1], aya);
      atomAddF(&agg1[b + 2], aza);
    } else if (c == 8) {
      atomAddF(&normb[dprev], ewa);
    }
  }
}

// ---------------- final node kernel ----------------
extern "C" __global__ __launch_bounds__(256) void k_node(
    const float* __restrict__ x, const float* __restrict__ xnorm,
    const float* __restrict__ agg0, const float* __restrict__ agg1,
    const float* __restrict__ normb, const float* __restrict__ Wm_s,
    const float* __restrict__ Wm_v, const float* __restrict__ Wu_s,
    const float* __restrict__ Wu_v, const float* __restrict__ Ws_s,
    const float* __restrict__ Ws_v, const float* __restrict__ res_scale_p,
    float* __restrict__ out, int N) {
  __shared__ float sWms[16 * 24];
  __shared__ float sWmv[64];
  __shared__ float sWus[256];
  __shared__ float sWuv[64];
  __shared__ float sWss[256];
  __shared__ float sWsv[64];
  int t = threadIdx.x;
  for (int i = t; i < 384; i += 256) sWms[i] = Wm_s[i];
  for (int i = t; i < 64; i += 256) sWmv[i] = Wm_v[i];
  for (int i = t; i < 256; i += 256) sWus[i] = Wu_s[i];
  for (int i = t; i < 64; i += 256) sWuv[i] = Wu_v[i];
  for (int i = t; i < 256; i += 256) sWss[i] = Ws_s[i];
  for (int i = t; i < 64; i += 256) sWsv[i] = Ws_v[i];
  __syncthreads();
  int n = blockIdx.x * 256 + t;
  if (n >= N) return;

  float inv = 1.0f / fmaxf(normb[n], EPSF);
  float a0[16], a1[24];
  {
    const float4* p0 = (const float4*)(agg0 + (long long)n * 16);
#pragma unroll
    for (int i = 0; i < 4; i++) ((float4*)a0)[i] = p0[i];
    const float4* p1 = (const float4*)(agg1 + (long long)n * 24);
#pragma unroll
    for (int i = 0; i < 6; i++) ((float4*)a1)[i] = p1[i];
  }
#pragma unroll
  for (int i = 0; i < 16; i++) a0[i] *= inv;
#pragma unroll
  for (int i = 0; i < 24; i++) a1[i] *= inv;

  float scal[16], gate[8];
#pragma unroll
  for (int jj = 0; jj < 24; jj++) {
    float acc = 0.f;
#pragma unroll
    for (int i = 0; i < 16; i++) acc += a0[i] * sWms[i * 24 + jj];
    acc *= Q16;
    if (jj < 16) scal[jj] = acc * sigm(acc);
    else gate[jj - 16] = sigm(acc);
  }
  float vg[24];
#pragma unroll
  for (int j = 0; j < 8; j++) {
    float g = gate[j];
#pragma unroll
    for (int cc = 0; cc < 3; cc++) {
      float acc = 0.f;
#pragma unroll
      for (int i = 0; i < 8; i++) acc += a1[i * 3 + cc] * sWmv[i * 8 + j];
      vg[j * 3 + cc] = acc * Q8 * g;
    }
  }
  float xn[40], xo[40];
  {
    const float4* pn = (const float4*)(xnorm + (long long)n * 40);
    const float4* po = (const float4*)(x + (long long)n * 40);
#pragma unroll
    for (int i = 0; i < 10; i++) { ((float4*)xn)[i] = pn[i]; ((float4*)xo)[i] = po[i]; }
  }
  float rs = res_scale_p[0];
  float o[40];
#pragma unroll
  for (int j = 0; j < 16; j++) {
    float acc = 0.f, acc2 = 0.f;
#pragma unroll
    for (int i = 0; i < 16; i++) {
      acc += scal[i] * sWus[i * 16 + j];
      acc2 += xn[i] * sWss[i * 16 + j];
    }
    o[j] = xo[j] + rs * ((acc + acc2) * Q16);
  }
#pragma unroll
  for (int j = 0; j < 8; j++) {
#pragma unroll
    for (int cc = 0; cc < 3; cc++) {
      float acc = 0.f;
#pragma unroll
      for (int i = 0; i < 8; i++)
        acc += vg[i * 3 + cc] * sWuv[i * 8 + j] + xn[16 + i * 3 + cc] * sWsv[i * 8 + j];
      o[16 + j * 3 + cc] = xo[16 + j * 3 + cc] + rs * (acc * Q8);
    }
  }
  float4* op = (float4*)(out + (long long)n * 40);
#pragma unroll
  for (int i = 0; i < 10; i++) op[i] = ((const float4*)o)[i];
}

// ---------------- launch ----------------
extern "C" void kernel_launch(void* const* d_in, const int* in_sizes, int n_in,
                              void* d_out, int out_size, void* d_ws, size_t ws_size,
                              hipStream_t stream) {
  const float* x = (const float*)d_in[0];
  const int* esrc = (const int*)d_in[1];
  const int* edst = (const int*)d_in[2];
  const float* sh = (const float*)d_in[3];
  const float* rbf = (const float*)d_in[4];
  const float* elen = (const float*)d_in[5];
  const float* w_r1 = (const float*)d_in[6];
  const float* b_r1 = (const float*)d_in[7];
  const float* w_r2 = (const float*)d_in[8];
  const float* b_r2 = (const float*)d_in[9];
  const float* w_g1 = (const float*)d_in[10];
  const float* b_g1 = (const float*)d_in[11];
  const float* w_g2 = (const float*)d_in[12];
  const float* b_g2 = (const float*)d_in[13];
  const float* Wm_s = (const float*)d_in[14];
  const float* Wm_v = (const float*)d_in[15];
  const float* Wu_s = (const float*)d_in[16];
  const float* Wu_v = (const float*)d_in[17];
  const float* Ws_s = (const float*)d_in[18];
  const float* Ws_v = (const float*)d_in[19];
  const float* res_scale = (const float*)d_in[20];

  const int N = in_sizes[0] / 40;
  const int E = in_sizes[1];
  const int NB = (N + 255) / 256;

  char* ws = (char*)d_ws;
  size_t off = 0;
  float* xnorm = (float*)(ws + off); off += (size_t)N * 40 * sizeof(float);
  off = (off + 255) & ~(size_t)255;
  float* agg0 = (float*)(ws + off); off += (size_t)N * 16 * sizeof(float);
  float* agg1 = (float*)(ws + off); off += (size_t)N * 24 * sizeof(float);
  float* normb = (float*)(ws + off); off += (size_t)N * sizeof(float);
  int* cnt = (int*)(ws + off); off += (size_t)N * sizeof(int);   // contiguous w/ agg: one memset
  off = (off + 255) & ~(size_t)255;
  f16* W2T = (f16*)(ws + off); off += (size_t)WNUM * 64 * sizeof(f16);
  off = (off + 255) & ~(size_t)255;
  int* offArr = (int*)(ws + off); off += (size_t)N * sizeof(int);
  int* cursor = (int*)(ws + off); off += (size_t)N * sizeof(int);
  int* bsum = (int*)(ws + off); off += 256 * sizeof(int);
  int* bsumx = (int*)(ws + off); off += 256 * sizeof(int);
  off = (off + 255) & ~(size_t)255;
  int* src_s = (int*)(ws + off); off += (size_t)E * sizeof(int);
  int* dst_s = (int*)(ws + off); off += (size_t)E * sizeof(int);
  float* elen_s = (float*)(ws + off); off += (size_t)E * sizeof(float);
  off = (off + 255) & ~(size_t)255;
  float* sh_s = (float*)(ws + off); off += (size_t)E * 4 * sizeof(float);
  float* rbf_s = (float*)(ws + off); off += (size_t)E * NRBF * sizeof(float);

  // zero agg0+agg1+normb+cnt in one shot (contiguous)
  hipMemsetAsync(agg0, 0, (size_t)N * 42 * sizeof(float), stream);

  k_prep_w2t<<<(HID * WNUM + 255) / 256, 256, 0, stream>>>(w_r2, W2T);
  k_xnorm<<<(N + 255) / 256, 256, 0, stream>>>(x, xnorm, N);

  // counting sort by dst
  k_hist<<<(E + 255) / 256, 256, 0, stream>>>(edst, cnt, E);
  k_scan1<<<NB, 256, 0, stream>>>(cnt, offArr, bsum, N);
  k_scan2<<<1, 256, 0, stream>>>(bsum, bsumx, NB);
  k_scan3<<<NB, 256, 0, stream>>>(offArr, bsumx, cursor, N);
  k_perm<<<(E + 255) / 256, 256, 0, stream>>>(esrc, edst, sh, rbf, elen, cursor,
                                              src_s, dst_s, sh_s, rbf_s, elen_s, E);

  int nblk = (E + 63) / 64;
  k_edge<<<nblk, 256, 0, stream>>>(xnorm, src_s, dst_s, sh_s, rbf_s, elen_s,
                                   w_r1, b_r1, w_g1, b_g1, w_g2, b_g2, b_r2, W2T,
                                   agg0, agg1, normb, E);

  k_node<<<(N + 255) / 256, 256, 0, stream>>>(x, xnorm, agg0, agg1, normb, Wm_s,
                                              Wm_v, Wu_s, Wu_v, Ws_s, Ws_v,
                                              res_scale, (float*)d_out, N);
}